// Round 1
// baseline (10257.486 us; speedup 1.0000x reference)
//
#include <hip/hip_runtime.h>
#include <hip/hip_bf16.h>

// Problem constants (fixed shapes)
#define NN 2048      // nodes
#define EE 65536     // edges
#define NF 128
#define BF 16
#define HH 512
#define NHH 8
#define HD 64
#define DEPTH 5

// ---------------- generic tiled f32 GEMM: C = A[M,K] @ B[K,N] + bias, optional ReLU
template<int RELU>
__global__ __launch_bounds__(256) void gemm64(const float* __restrict__ A,
                                              const float* __restrict__ B,
                                              const float* __restrict__ bias,
                                              float* __restrict__ C,
                                              int M, int N, int K) {
    __shared__ float As[8][65];
    __shared__ float Bs[8][65];
    int t = threadIdx.x;
    int tx = t & 15, ty = t >> 4;
    int n0 = blockIdx.x * 64, m0 = blockIdx.y * 64;
    float acc[4][4] = {};
    for (int k0 = 0; k0 < K; k0 += 8) {
        for (int i = t; i < 512; i += 256) {
            int r = i >> 3, kk = i & 7;
            As[kk][r] = A[(size_t)(m0 + r) * K + k0 + kk];
        }
        for (int i = t; i < 512; i += 256) {
            int kk = i >> 6, c = i & 63;
            Bs[kk][c] = B[(size_t)(k0 + kk) * N + n0 + c];
        }
        __syncthreads();
#pragma unroll
        for (int kk = 0; kk < 8; ++kk) {
            float a[4], b[4];
#pragma unroll
            for (int i = 0; i < 4; ++i) a[i] = As[kk][ty * 4 + i];
#pragma unroll
            for (int j = 0; j < 4; ++j) b[j] = Bs[kk][tx * 4 + j];
#pragma unroll
            for (int i = 0; i < 4; ++i)
#pragma unroll
                for (int j = 0; j < 4; ++j) acc[i][j] += a[i] * b[j];
        }
        __syncthreads();
    }
#pragma unroll
    for (int i = 0; i < 4; ++i) {
        int m = m0 + ty * 4 + i;
#pragma unroll
        for (int j = 0; j < 4; ++j) {
            int n = n0 + tx * 4 + j;
            float v = acc[i][j] + bias[n];
            if (RELU) v = fmaxf(v, 0.f);
            C[(size_t)m * N + n] = v;
        }
    }
}

// ---------------- e_bias = edge_attr @ We + be   [E,16]x[16,8]
__global__ __launch_bounds__(256) void ebias_kernel(const float* __restrict__ ea,
                                                    const float* __restrict__ We,
                                                    const float* __restrict__ be,
                                                    float* __restrict__ eb) {
    int e = blockIdx.x * 256 + threadIdx.x;
    float a[16];
#pragma unroll
    for (int i = 0; i < 16; ++i) a[i] = ea[(size_t)e * 16 + i];
#pragma unroll
    for (int j = 0; j < 8; ++j) {
        float s = be[j];
#pragma unroll
        for (int i = 0; i < 16; ++i) s += a[i] * We[i * 8 + j];
        eb[(size_t)e * 8 + j] = s;
    }
}

// ---------------- dedupe: last edge index wins per (src,dst)
__global__ __launch_bounds__(256) void amax_kernel(const int* __restrict__ eidx, int* __restrict__ lastE) {
    int e = blockIdx.x * 256 + threadIdx.x;
    int s = eidx[e], d = eidx[EE + e];
    atomicMax(&lastE[s * NN + d], e);
}

__global__ __launch_bounds__(256) void count_kernel(const int* __restrict__ eidx,
                                                    const int* __restrict__ lastE,
                                                    int* __restrict__ cnt) {
    int e = blockIdx.x * 256 + threadIdx.x;
    int s = eidx[e], d = eidx[EE + e];
    if (lastE[s * NN + d] == e) atomicAdd(&cnt[s], 1);
}

__global__ __launch_bounds__(256) void scan2048(const int* __restrict__ cnt,
                                                int* __restrict__ rowptr,
                                                int* __restrict__ rowoff) {
    __shared__ int sums[256];
    int t = threadIdx.x;
    int loc[8];
    int s = 0;
#pragma unroll
    for (int i = 0; i < 8; ++i) { loc[i] = s; s += cnt[t * 8 + i]; }
    sums[t] = s;
    __syncthreads();
    for (int off = 1; off < 256; off <<= 1) {
        int v = (t >= off) ? sums[t - off] : 0;
        __syncthreads();
        sums[t] += v;
        __syncthreads();
    }
    int base = (t == 0) ? 0 : sums[t - 1];
#pragma unroll
    for (int i = 0; i < 8; ++i) { rowptr[t * 8 + i] = base + loc[i]; rowoff[t * 8 + i] = base + loc[i]; }
    if (t == 255) rowptr[NN] = sums[255];
}

__global__ __launch_bounds__(256) void fill_kernel(const int* __restrict__ eidx,
                                                   const int* __restrict__ lastE,
                                                   const float* __restrict__ eb,
                                                   int* __restrict__ rowoff,
                                                   int* __restrict__ csr_dst,
                                                   float* __restrict__ csr_b) {
    int e = blockIdx.x * 256 + threadIdx.x;
    int s = eidx[e], d = eidx[EE + e];
    if (lastE[s * NN + d] == e) {
        int pos = atomicAdd(&rowoff[s], 1);
        csr_dst[pos] = d;
#pragma unroll
        for (int j = 0; j < 8; ++j) csr_b[(size_t)pos * 8 + j] = eb[(size_t)e * 8 + j];
    }
}

// ---------------- fused attention: per (head, 32-row block); two-pass online softmax
// scores = (Q Kt)*scale + sparse bias; out = softmax(scores) @ V
__global__ __launch_bounds__(256) void attn_kernel(const float* __restrict__ q,
                                                   const float* __restrict__ k,
                                                   const float* __restrict__ v,
                                                   const int* __restrict__ rowptr,
                                                   const int* __restrict__ csr_dst,
                                                   const float* __restrict__ csr_b,
                                                   float* __restrict__ ao) {
    const int head = blockIdx.x;
    const int n0 = blockIdx.y * 32;
    const int t = threadIdx.x;
    const int w = t >> 6, lane = t & 63;
    const float scale = 0.125f;  // 1/sqrt(64)

    __shared__ float Qs[32][HD];
    __shared__ float Ks[64][HD + 1];
    __shared__ float Vs[64][HD + 1];
    __shared__ float Ss[32][64 + 1];

    for (int i = t; i < 32 * HD; i += 256) {
        int r = i >> 6, d = i & 63;
        Qs[r][d] = q[(size_t)(n0 + r) * HH + head * HD + d];
    }
    float M[8], S[8];
#pragma unroll
    for (int rr = 0; rr < 8; ++rr) { M[rr] = -1e30f; S[rr] = 0.f; }
    __syncthreads();

    // ---- pass 1: running max / sum
    for (int m0 = 0; m0 < NN; m0 += 64) {
        for (int i = t; i < 64 * HD; i += 256) {
            int c = i >> 6, d = i & 63;
            Ks[c][d] = k[(size_t)(m0 + c) * HH + head * HD + d];
        }
        __syncthreads();
#pragma unroll
        for (int rr = 0; rr < 8; ++rr) {
            int r = w * 8 + rr;
            float acc = 0.f;
#pragma unroll
            for (int d = 0; d < HD; ++d) acc += Qs[r][d] * Ks[lane][d];
            Ss[r][lane] = acc * scale;
        }
        __syncthreads();
        {   // sparse bias scatter: 8 threads per row
            int r = t >> 3, j = t & 7;
            int gr = n0 + r;
            int e0 = rowptr[gr], e1 = rowptr[gr + 1];
            for (int e = e0 + j; e < e1; e += 8) {
                unsigned dd = (unsigned)(csr_dst[e] - m0);
                if (dd < 64u) Ss[r][dd] += csr_b[(size_t)e * 8 + head];
            }
        }
        __syncthreads();
#pragma unroll
        for (int rr = 0; rr < 8; ++rr) {
            int r = w * 8 + rr;
            float s = Ss[r][lane];
            float tm = s;
#pragma unroll
            for (int off = 32; off > 0; off >>= 1) tm = fmaxf(tm, __shfl_xor(tm, off, 64));
            float nm = fmaxf(M[rr], tm);
            float e = __expf(s - nm);
            float ts = e;
#pragma unroll
            for (int off = 32; off > 0; off >>= 1) ts += __shfl_xor(ts, off, 64);
            S[rr] = S[rr] * __expf(M[rr] - nm) + ts;
            M[rr] = nm;
        }
        __syncthreads();
    }
    float Sinv[8];
#pragma unroll
    for (int rr = 0; rr < 8; ++rr) Sinv[rr] = 1.f / S[rr];
    float acc[8];
#pragma unroll
    for (int rr = 0; rr < 8; ++rr) acc[rr] = 0.f;

    // ---- pass 2: recompute scores -> p, accumulate PV
    for (int m0 = 0; m0 < NN; m0 += 64) {
        for (int i = t; i < 64 * HD; i += 256) {
            int c = i >> 6, d = i & 63;
            Ks[c][d] = k[(size_t)(m0 + c) * HH + head * HD + d];
            Vs[c][d] = v[(size_t)(m0 + c) * HH + head * HD + d];
        }
        __syncthreads();
#pragma unroll
        for (int rr = 0; rr < 8; ++rr) {
            int r = w * 8 + rr;
            float a2 = 0.f;
#pragma unroll
            for (int d = 0; d < HD; ++d) a2 += Qs[r][d] * Ks[lane][d];
            Ss[r][lane] = a2 * scale;
        }
        __syncthreads();
        {
            int r = t >> 3, j = t & 7;
            int gr = n0 + r;
            int e0 = rowptr[gr], e1 = rowptr[gr + 1];
            for (int e = e0 + j; e < e1; e += 8) {
                unsigned dd = (unsigned)(csr_dst[e] - m0);
                if (dd < 64u) Ss[r][dd] += csr_b[(size_t)e * 8 + head];
            }
        }
        __syncthreads();
#pragma unroll
        for (int rr = 0; rr < 8; ++rr) {
            int r = w * 8 + rr;
            float s = Ss[r][lane];
            Ss[r][lane] = __expf(s - M[rr]) * Sinv[rr];
        }
        __syncthreads();
#pragma unroll
        for (int rr = 0; rr < 8; ++rr) {
            int r = w * 8 + rr;
            float a2 = acc[rr];
#pragma unroll
            for (int mm = 0; mm < 64; ++mm) a2 += Ss[r][mm] * Vs[mm][lane];
            acc[rr] = a2;
        }
        __syncthreads();
    }
#pragma unroll
    for (int rr = 0; rr < 8; ++rr) {
        int r = w * 8 + rr;
        ao[(size_t)(n0 + r) * HH + head * HD + lane] = acc[rr];
    }
}

// ---------------- LayerNorm(out = LN(a + b) * g + be), rows of 512
__global__ __launch_bounds__(256) void ln_kernel(const float* __restrict__ a,
                                                 const float* __restrict__ b,
                                                 const float* __restrict__ g,
                                                 const float* __restrict__ be,
                                                 float* __restrict__ out) {
    int row = blockIdx.x * 4 + (threadIdx.x >> 6);
    int lane = threadIdx.x & 63;
    const float* pa = a + (size_t)row * HH;
    const float* pb = b + (size_t)row * HH;
    float x[8];
    float s = 0.f;
#pragma unroll
    for (int i = 0; i < 8; ++i) { x[i] = pa[lane + i * 64] + pb[lane + i * 64]; s += x[i]; }
#pragma unroll
    for (int off = 32; off > 0; off >>= 1) s += __shfl_xor(s, off, 64);
    float mean = s * (1.f / 512.f);
    float vs = 0.f;
#pragma unroll
    for (int i = 0; i < 8; ++i) { float d = x[i] - mean; vs += d * d; }
#pragma unroll
    for (int off = 32; off > 0; off >>= 1) vs += __shfl_xor(vs, off, 64);
    float rs = rsqrtf(vs * (1.f / 512.f) + 1e-5f);
    float* po = out + (size_t)row * HH;
#pragma unroll
    for (int i = 0; i < 8; ++i)
        po[lane + i * 64] = (x[i] - mean) * rs * g[lane + i * 64] + be[lane + i * 64];
}

extern "C" void kernel_launch(void* const* d_in, const int* in_sizes, int n_in,
                              void* d_out, int out_size, void* d_ws, size_t ws_size,
                              hipStream_t stream) {
    const float* x   = (const float*)d_in[0];
    const int*  eidx = (const int*)d_in[1];
    const float* ea  = (const float*)d_in[2];
    const float* Wn = (const float*)d_in[3];  const float* bn = (const float*)d_in[4];
    const float* We = (const float*)d_in[5];  const float* be = (const float*)d_in[6];
    const float* Wq = (const float*)d_in[7];  const float* bq = (const float*)d_in[8];
    const float* Wk = (const float*)d_in[9];  const float* bk = (const float*)d_in[10];
    const float* Wv = (const float*)d_in[11]; const float* bv = (const float*)d_in[12];
    const float* Wo = (const float*)d_in[13]; const float* bo = (const float*)d_in[14];
    const float* W1 = (const float*)d_in[15]; const float* b1 = (const float*)d_in[16];
    const float* W2 = (const float*)d_in[17]; const float* b2 = (const float*)d_in[18];
    const float* g1 = (const float*)d_in[19]; const float* be1 = (const float*)d_in[20];
    const float* g2 = (const float*)d_in[21]; const float* be2 = (const float*)d_in[22];
    float* out = (float*)d_out;

    // workspace carve (bytes, 256-aligned)
    char* base = (char*)d_ws;
    size_t off = 0;
    auto carve = [&](size_t bytes) { void* p = base + off; off = (off + bytes + 255) & ~(size_t)255; return p; };
    float* h   = (float*)carve((size_t)NN * HH * 4);
    float* q   = (float*)carve((size_t)NN * HH * 4);
    float* k   = (float*)carve((size_t)NN * HH * 4);
    float* v   = (float*)carve((size_t)NN * HH * 4);
    float* ao  = (float*)carve((size_t)NN * HH * 4);
    float* po  = (float*)carve((size_t)NN * HH * 4);
    float* ff1 = (float*)carve((size_t)NN * 4 * HH * 4);   // 16 MB, reused as lastE during setup
    float* eb  = (float*)carve((size_t)EE * NHH * 4);
    float* csr_b = (float*)carve((size_t)EE * NHH * 4);
    int* cnt    = (int*)carve((size_t)NN * 4);
    int* rowptr = (int*)carve((size_t)(NN + 1) * 4);
    int* rowoff = (int*)carve((size_t)NN * 4);
    int* csr_dst = (int*)carve((size_t)EE * 4);
    int* lastE = (int*)ff1;  // setup-phase alias (both 16 MB; setup completes before FF runs)

    // ---- setup
    hipMemsetAsync(lastE, 0xFF, (size_t)NN * NN * 4, stream);   // -1
    hipMemsetAsync(cnt, 0, (size_t)NN * 4, stream);

    gemm64<0><<<dim3(HH / 64, NN / 64), 256, 0, stream>>>(x, Wn, bn, h, NN, HH, NF);
    ebias_kernel<<<EE / 256, 256, 0, stream>>>(ea, We, be, eb);
    amax_kernel<<<EE / 256, 256, 0, stream>>>(eidx, lastE);
    count_kernel<<<EE / 256, 256, 0, stream>>>(eidx, lastE, cnt);
    scan2048<<<1, 256, 0, stream>>>(cnt, rowptr, rowoff);
    fill_kernel<<<EE / 256, 256, 0, stream>>>(eidx, lastE, eb, rowoff, csr_dst, csr_b);

    // ---- transformer layers
    for (int d = 0; d < DEPTH; ++d) {
        gemm64<0><<<dim3(HH / 64, NN / 64), 256, 0, stream>>>(h, Wq, bq, q, NN, HH, HH);
        gemm64<0><<<dim3(HH / 64, NN / 64), 256, 0, stream>>>(h, Wk, bk, k, NN, HH, HH);
        gemm64<0><<<dim3(HH / 64, NN / 64), 256, 0, stream>>>(h, Wv, bv, v, NN, HH, HH);
        attn_kernel<<<dim3(NHH, NN / 32), 256, 0, stream>>>(q, k, v, rowptr, csr_dst, csr_b, ao);
        gemm64<0><<<dim3(HH / 64, NN / 64), 256, 0, stream>>>(ao, Wo, bo, po, NN, HH, HH);
        ln_kernel<<<NN / 4, 256, 0, stream>>>(h, po, g1, be1, h);
        gemm64<1><<<dim3(4 * HH / 64, NN / 64), 256, 0, stream>>>(h, W1, b1, ff1, NN, 4 * HH, HH);
        gemm64<0><<<dim3(HH / 64, NN / 64), 256, 0, stream>>>(ff1, W2, b2, po, NN, HH, 4 * HH);
        float* dst = (d == DEPTH - 1) ? out : h;
        ln_kernel<<<NN / 4, 256, 0, stream>>>(h, po, g2, be2, dst);
    }
    (void)in_sizes; (void)n_in; (void)out_size; (void)ws_size;
}

// Round 2
// 4779.198 us; speedup vs baseline: 2.1463x; 2.1463x over previous
//
#include <hip/hip_runtime.h>
#include <hip/hip_bf16.h>

// Problem constants (fixed shapes)
#define NN 2048      // nodes
#define EE 65536     // edges
#define NF_ 128
#define HH 512
#define NHH 8
#define HD 64
#define DEPTH 5

typedef __attribute__((ext_vector_type(8))) short bf16x8;
typedef __attribute__((ext_vector_type(4))) float f32x4;

__device__ __forceinline__ ushort f2bf(float x) {
    uint u = __builtin_bit_cast(uint, x);
    u += 0x7fffu + ((u >> 16) & 1u);
    return (ushort)(u >> 16);
}

// ---------------- tiled f32 GEMM: C = A[M,K] @ B[K,N] + bias
// OUT=0: f32 row-major C. OUT=1: bf16 head-major Cb[h][m][d]. OUT=2: bf16 transposed Cb[h][d][m].
template<int RELU, int OUT>
__global__ __launch_bounds__(256) void gemm64(const float* __restrict__ A,
                                              const float* __restrict__ B,
                                              const float* __restrict__ bias,
                                              float* __restrict__ C,
                                              ushort* __restrict__ Cb,
                                              int M, int N, int K) {
    __shared__ float As[8][65];
    __shared__ float Bs[8][65];
    int t = threadIdx.x;
    int tx = t & 15, ty = t >> 4;
    int n0 = blockIdx.x * 64, m0 = blockIdx.y * 64;
    float acc[4][4] = {};
    for (int k0 = 0; k0 < K; k0 += 8) {
        for (int i = t; i < 512; i += 256) {
            int r = i >> 3, kk = i & 7;
            As[kk][r] = A[(size_t)(m0 + r) * K + k0 + kk];
        }
        for (int i = t; i < 512; i += 256) {
            int kk = i >> 6, c = i & 63;
            Bs[kk][c] = B[(size_t)(k0 + kk) * N + n0 + c];
        }
        __syncthreads();
#pragma unroll
        for (int kk = 0; kk < 8; ++kk) {
            float a[4], b[4];
#pragma unroll
            for (int i = 0; i < 4; ++i) a[i] = As[kk][ty * 4 + i];
#pragma unroll
            for (int j = 0; j < 4; ++j) b[j] = Bs[kk][tx * 4 + j];
#pragma unroll
            for (int i = 0; i < 4; ++i)
#pragma unroll
                for (int j = 0; j < 4; ++j) acc[i][j] += a[i] * b[j];
        }
        __syncthreads();
    }
#pragma unroll
    for (int i = 0; i < 4; ++i) {
        int m = m0 + ty * 4 + i;
#pragma unroll
        for (int j = 0; j < 4; ++j) {
            int n = n0 + tx * 4 + j;
            float v = acc[i][j] + bias[n];
            if (RELU) v = fmaxf(v, 0.f);
            if (OUT == 0) {
                C[(size_t)m * N + n] = v;
            } else if (OUT == 1) {
                Cb[((size_t)(n >> 6) * NN + m) * 64 + (n & 63)] = f2bf(v);
            } else {
                Cb[((size_t)(n >> 6) * 64 + (n & 63)) * NN + m] = f2bf(v);
            }
        }
    }
}

// ---------------- e_bias = edge_attr @ We + be   [E,16]x[16,8]
__global__ __launch_bounds__(256) void ebias_kernel(const float* __restrict__ ea,
                                                    const float* __restrict__ We,
                                                    const float* __restrict__ be,
                                                    float* __restrict__ eb) {
    int e = blockIdx.x * 256 + threadIdx.x;
    float a[16];
#pragma unroll
    for (int i = 0; i < 16; ++i) a[i] = ea[(size_t)e * 16 + i];
#pragma unroll
    for (int j = 0; j < 8; ++j) {
        float s = be[j];
#pragma unroll
        for (int i = 0; i < 16; ++i) s += a[i] * We[i * 8 + j];
        eb[(size_t)e * 8 + j] = s;
    }
}

// ---------------- dedupe: last edge index wins per (src,dst)
__global__ __launch_bounds__(256) void amax_kernel(const int* __restrict__ eidx, int* __restrict__ lastE) {
    int e = blockIdx.x * 256 + threadIdx.x;
    int s = eidx[e], d = eidx[EE + e];
    atomicMax(&lastE[s * NN + d], e);
}

__global__ __launch_bounds__(256) void count_kernel(const int* __restrict__ eidx,
                                                    const int* __restrict__ lastE,
                                                    int* __restrict__ cnt) {
    int e = blockIdx.x * 256 + threadIdx.x;
    int s = eidx[e], d = eidx[EE + e];
    if (lastE[s * NN + d] == e) atomicAdd(&cnt[s], 1);
}

__global__ __launch_bounds__(256) void scan2048(const int* __restrict__ cnt,
                                                int* __restrict__ rowptr,
                                                int* __restrict__ rowoff) {
    __shared__ int sums[256];
    int t = threadIdx.x;
    int loc[8];
    int s = 0;
#pragma unroll
    for (int i = 0; i < 8; ++i) { loc[i] = s; s += cnt[t * 8 + i]; }
    sums[t] = s;
    __syncthreads();
    for (int off = 1; off < 256; off <<= 1) {
        int v = (t >= off) ? sums[t - off] : 0;
        __syncthreads();
        sums[t] += v;
        __syncthreads();
    }
    int base = (t == 0) ? 0 : sums[t - 1];
#pragma unroll
    for (int i = 0; i < 8; ++i) { rowptr[t * 8 + i] = base + loc[i]; rowoff[t * 8 + i] = base + loc[i]; }
    if (t == 255) rowptr[NN] = sums[255];
}

__global__ __launch_bounds__(256) void fill_kernel(const int* __restrict__ eidx,
                                                   const int* __restrict__ lastE,
                                                   int* __restrict__ rowoff,
                                                   int* __restrict__ csr_dst,
                                                   int* __restrict__ csr_eid) {
    int e = blockIdx.x * 256 + threadIdx.x;
    int s = eidx[e], d = eidx[EE + e];
    if (lastE[s * NN + d] == e) {
        int pos = atomicAdd(&rowoff[s], 1);
        csr_dst[pos] = d;
        csr_eid[pos] = e;
    }
}

// per-row insertion sort by dst (winners have unique dst -> deterministic result)
__global__ __launch_bounds__(256) void sort_kernel(const int* __restrict__ rowptr,
                                                   int* __restrict__ dst,
                                                   int* __restrict__ eid) {
    int r = blockIdx.x * 256 + threadIdx.x;
    if (r >= NN) return;
    int s = rowptr[r], e = rowptr[r + 1];
    for (int i = s + 1; i < e; ++i) {
        int d = dst[i], id = eid[i];
        int j = i - 1;
        while (j >= s && dst[j] > d) { dst[j + 1] = dst[j]; eid[j + 1] = eid[j]; --j; }
        dst[j + 1] = d; eid[j + 1] = id;
    }
}

__global__ __launch_bounds__(256) void gather_kernel(const int* __restrict__ rowptr,
                                                     const int* __restrict__ eid,
                                                     const float* __restrict__ eb,
                                                     float* __restrict__ csr_b) {
    int idx = blockIdx.x * 256 + threadIdx.x;
    int pos = idx >> 3, j = idx & 7;
    if (pos < rowptr[NN])
        csr_b[(size_t)pos * 8 + j] = eb[(size_t)eid[pos] * 8 + j];
}

// ---------------- one-pass flash attention with MFMA bf16
// Q: qb[h][n][d], K: kb[h][n][d], V transposed: vtb[h][d][n]  (all bf16)
// per block: head, 32 query rows; stream 64-key tiles; online softmax; sparse bias via sorted CSR cursor
__global__ __launch_bounds__(256) void attn_mfma(const ushort* __restrict__ qb,
                                                 const ushort* __restrict__ kb,
                                                 const ushort* __restrict__ vtb,
                                                 const int* __restrict__ rowptr,
                                                 const int* __restrict__ csr_dst,
                                                 const float* __restrict__ csr_b,
                                                 float* __restrict__ ao) {
    const int head = blockIdx.x;
    const int n0 = blockIdx.y * 32;
    const int t = threadIdx.x;
    const int w = t >> 6, l = t & 63;
    const int mh = w & 1, nh = w >> 1;   // (row-half, col-half) quadrant per wave

    __shared__ __align__(16) ushort Ks[64][72];   // [key][dim], padded
    __shared__ __align__(16) ushort Vts[64][72];  // [dim][key], padded
    __shared__ __align__(16) float  Sl[32][68];   // score tile f32
    __shared__ __align__(16) ushort Pb[32][72];   // P tile bf16
    __shared__ float Mrow[32], Srow[32], Frow[32];
    __shared__ int   cur[32];

    // Q fragments (persistent): lane l holds Q[mh*16 + (l&15)][(l>>4)*8 + ks*32 .. +7]
    bf16x8 qf0, qf1;
    {
        int r = n0 + mh * 16 + (l & 15);
        const ushort* qp = qb + ((size_t)head * NN + r) * HD + ((l >> 4) * 8);
        qf0 = *(const bf16x8*)qp;
        qf1 = *(const bf16x8*)(qp + 32);
    }
    if (t < 32) { Mrow[t] = -1e30f; Srow[t] = 0.f; cur[t] = rowptr[n0 + t]; }
    f32x4 o0 = {0.f, 0.f, 0.f, 0.f}, o1 = {0.f, 0.f, 0.f, 0.f};
    __syncthreads();

    for (int m0 = 0; m0 < NN; m0 += 64) {
        // ---- stage K tile [64 keys][64 dims] and Vt tile [64 dims][64 keys]
        {
            const uint* kp = (const uint*)(kb + ((size_t)head * NN + m0) * HD);
            const uint* vp = (const uint*)vtb;
#pragma unroll
            for (int i = t; i < 2048; i += 256) {
                int r = i >> 5, c = i & 31;
                ((uint*)&Ks[r][0])[c] = kp[r * 32 + c];
                ((uint*)&Vts[r][0])[c] = vp[(((size_t)head * HD + r) * NN + m0) / 2 + c];
            }
        }
        __syncthreads();
        // ---- QK^T: wave quadrant (mh,nh): rows mh*16..+15, cols nh*32..+31
        {
            int dimb = (l >> 4) * 8;
            int key0 = nh * 32 + (l & 15);
            bf16x8 ka0 = *(const bf16x8*)&Ks[key0][dimb];
            bf16x8 ka1 = *(const bf16x8*)&Ks[key0][dimb + 32];
            bf16x8 kb0 = *(const bf16x8*)&Ks[key0 + 16][dimb];
            bf16x8 kb1 = *(const bf16x8*)&Ks[key0 + 16][dimb + 32];
            f32x4 s0 = {0.f, 0.f, 0.f, 0.f}, s1 = {0.f, 0.f, 0.f, 0.f};
            s0 = __builtin_amdgcn_mfma_f32_16x16x32_bf16(qf0, ka0, s0, 0, 0, 0);
            s0 = __builtin_amdgcn_mfma_f32_16x16x32_bf16(qf1, ka1, s0, 0, 0, 0);
            s1 = __builtin_amdgcn_mfma_f32_16x16x32_bf16(qf0, kb0, s1, 0, 0, 0);
            s1 = __builtin_amdgcn_mfma_f32_16x16x32_bf16(qf1, kb1, s1, 0, 0, 0);
            int row = mh * 16 + (l >> 4) * 4;
            int c0 = nh * 32 + (l & 15);
#pragma unroll
            for (int j = 0; j < 4; ++j) {
                Sl[row + j][c0] = s0[j] * 0.125f;
                Sl[row + j][c0 + 16] = s1[j] * 0.125f;
            }
        }
        __syncthreads();
        // ---- sparse bias scatter (sorted CSR, per-row cursor)
        if (t < 32) {
            int c = cur[t], end = rowptr[n0 + t + 1];
            int lim = m0 + 64;
            while (c < end) {
                int dd = csr_dst[c];
                if (dd >= lim) break;
                Sl[t][dd - m0] += csr_b[(size_t)c * 8 + head];
                ++c;
            }
            cur[t] = c;
        }
        __syncthreads();
        // ---- online softmax: 8 threads per row, 8 cols each
        {
            int r = t >> 3, j = t & 7;
            f32x4 a = *(const f32x4*)&Sl[r][j * 8];
            f32x4 b = *(const f32x4*)&Sl[r][j * 8 + 4];
            float tm = fmaxf(fmaxf(fmaxf(a[0], a[1]), fmaxf(a[2], a[3])),
                             fmaxf(fmaxf(b[0], b[1]), fmaxf(b[2], b[3])));
            tm = fmaxf(tm, __shfl_xor(tm, 1, 64));
            tm = fmaxf(tm, __shfl_xor(tm, 2, 64));
            tm = fmaxf(tm, __shfl_xor(tm, 4, 64));
            float Mo = Mrow[r];
            float Mn = fmaxf(Mo, tm);
            float p[8];
#pragma unroll
            for (int i = 0; i < 4; ++i) p[i] = __expf(a[i] - Mn);
#pragma unroll
            for (int i = 0; i < 4; ++i) p[4 + i] = __expf(b[i] - Mn);
            float ts = 0.f;
#pragma unroll
            for (int i = 0; i < 8; ++i) ts += p[i];
            ts += __shfl_xor(ts, 1, 64);
            ts += __shfl_xor(ts, 2, 64);
            ts += __shfl_xor(ts, 4, 64);
            int4 pk;
            pk.x = (int)((uint)f2bf(p[0]) | ((uint)f2bf(p[1]) << 16));
            pk.y = (int)((uint)f2bf(p[2]) | ((uint)f2bf(p[3]) << 16));
            pk.z = (int)((uint)f2bf(p[4]) | ((uint)f2bf(p[5]) << 16));
            pk.w = (int)((uint)f2bf(p[6]) | ((uint)f2bf(p[7]) << 16));
            *(int4*)&Pb[r][j * 8] = pk;
            if (j == 0) {
                float f = __expf(Mo - Mn);
                Mrow[r] = Mn;
                Srow[r] = Srow[r] * f + ts;
                Frow[r] = f;
            }
        }
        __syncthreads();
        // ---- rescale accumulator + PV
        {
            int row4 = mh * 16 + (l >> 4) * 4;
#pragma unroll
            for (int j = 0; j < 4; ++j) {
                float fj = Frow[row4 + j];
                o0[j] *= fj;
                o1[j] *= fj;
            }
            int kbase = (l >> 4) * 8;
            int prow = mh * 16 + (l & 15);
            bf16x8 p0 = *(const bf16x8*)&Pb[prow][kbase];
            bf16x8 p1 = *(const bf16x8*)&Pb[prow][kbase + 32];
            int d0 = nh * 32 + (l & 15);
            bf16x8 v00 = *(const bf16x8*)&Vts[d0][kbase];
            bf16x8 v01 = *(const bf16x8*)&Vts[d0][kbase + 32];
            bf16x8 v10 = *(const bf16x8*)&Vts[d0 + 16][kbase];
            bf16x8 v11 = *(const bf16x8*)&Vts[d0 + 16][kbase + 32];
            o0 = __builtin_amdgcn_mfma_f32_16x16x32_bf16(p0, v00, o0, 0, 0, 0);
            o0 = __builtin_amdgcn_mfma_f32_16x16x32_bf16(p1, v01, o0, 0, 0, 0);
            o1 = __builtin_amdgcn_mfma_f32_16x16x32_bf16(p0, v10, o1, 0, 0, 0);
            o1 = __builtin_amdgcn_mfma_f32_16x16x32_bf16(p1, v11, o1, 0, 0, 0);
        }
        __syncthreads();
    }
    // ---- write out (divide by softmax sum)
    {
        int row4 = mh * 16 + (l >> 4) * 4;
        int c0 = nh * 32 + (l & 15);
#pragma unroll
        for (int j = 0; j < 4; ++j) {
            int r = row4 + j;
            float inv = 1.f / Srow[r];
            float* dst = ao + (size_t)(n0 + r) * HH + head * HD;
            dst[c0] = o0[j] * inv;
            dst[c0 + 16] = o1[j] * inv;
        }
    }
}

// ---------------- LayerNorm(out = LN(a + b) * g + be), rows of 512
__global__ __launch_bounds__(256) void ln_kernel(const float* __restrict__ a,
                                                 const float* __restrict__ b,
                                                 const float* __restrict__ g,
                                                 const float* __restrict__ be,
                                                 float* __restrict__ out) {
    int row = blockIdx.x * 4 + (threadIdx.x >> 6);
    int lane = threadIdx.x & 63;
    const float* pa = a + (size_t)row * HH;
    const float* pb = b + (size_t)row * HH;
    float x[8];
    float s = 0.f;
#pragma unroll
    for (int i = 0; i < 8; ++i) { x[i] = pa[lane + i * 64] + pb[lane + i * 64]; s += x[i]; }
#pragma unroll
    for (int off = 32; off > 0; off >>= 1) s += __shfl_xor(s, off, 64);
    float mean = s * (1.f / 512.f);
    float vs = 0.f;
#pragma unroll
    for (int i = 0; i < 8; ++i) { float d = x[i] - mean; vs += d * d; }
#pragma unroll
    for (int off = 32; off > 0; off >>= 1) vs += __shfl_xor(vs, off, 64);
    float rs = rsqrtf(vs * (1.f / 512.f) + 1e-5f);
    float* po = out + (size_t)row * HH;
#pragma unroll
    for (int i = 0; i < 8; ++i)
        po[lane + i * 64] = (x[i] - mean) * rs * g[lane + i * 64] + be[lane + i * 64];
}

extern "C" void kernel_launch(void* const* d_in, const int* in_sizes, int n_in,
                              void* d_out, int out_size, void* d_ws, size_t ws_size,
                              hipStream_t stream) {
    const float* x   = (const float*)d_in[0];
    const int*  eidx = (const int*)d_in[1];
    const float* ea  = (const float*)d_in[2];
    const float* Wn = (const float*)d_in[3];  const float* bn = (const float*)d_in[4];
    const float* We = (const float*)d_in[5];  const float* be = (const float*)d_in[6];
    const float* Wq = (const float*)d_in[7];  const float* bq = (const float*)d_in[8];
    const float* Wk = (const float*)d_in[9];  const float* bk = (const float*)d_in[10];
    const float* Wv = (const float*)d_in[11]; const float* bv = (const float*)d_in[12];
    const float* Wo = (const float*)d_in[13]; const float* bo = (const float*)d_in[14];
    const float* W1 = (const float*)d_in[15]; const float* b1 = (const float*)d_in[16];
    const float* W2 = (const float*)d_in[17]; const float* b2 = (const float*)d_in[18];
    const float* g1 = (const float*)d_in[19]; const float* be1 = (const float*)d_in[20];
    const float* g2 = (const float*)d_in[21]; const float* be2 = (const float*)d_in[22];
    float* out = (float*)d_out;

    // workspace carve (bytes, 256-aligned)
    char* base = (char*)d_ws;
    size_t off = 0;
    auto carve = [&](size_t bytes) { void* p = base + off; off = (off + bytes + 255) & ~(size_t)255; return p; };
    float* h   = (float*)carve((size_t)NN * HH * 4);
    float* ao  = (float*)carve((size_t)NN * HH * 4);
    float* po  = (float*)carve((size_t)NN * HH * 4);
    float* ff1 = (float*)carve((size_t)NN * 4 * HH * 4);   // 16 MB, aliased as lastE during setup
    float* eb  = (float*)carve((size_t)EE * NHH * 4);
    float* csr_b = (float*)carve((size_t)EE * NHH * 4);
    ushort* qb  = (ushort*)carve((size_t)NN * HH * 2);
    ushort* kbf = (ushort*)carve((size_t)NN * HH * 2);
    ushort* vtb = (ushort*)carve((size_t)NN * HH * 2);
    int* cnt    = (int*)carve((size_t)NN * 4);
    int* rowptr = (int*)carve((size_t)(NN + 1) * 4);
    int* rowoff = (int*)carve((size_t)NN * 4);
    int* csr_dst = (int*)carve((size_t)EE * 4);
    int* csr_eid = (int*)carve((size_t)EE * 4);
    int* lastE = (int*)ff1;  // setup-phase alias (NN*NN*4 = 16MB = ff1 size)

    // ---- setup
    hipMemsetAsync(lastE, 0xFF, (size_t)NN * NN * 4, stream);   // -1
    hipMemsetAsync(cnt, 0, (size_t)NN * 4, stream);

    gemm64<0, 0><<<dim3(HH / 64, NN / 64), 256, 0, stream>>>(x, Wn, bn, h, nullptr, NN, HH, NF_);
    ebias_kernel<<<EE / 256, 256, 0, stream>>>(ea, We, be, eb);
    amax_kernel<<<EE / 256, 256, 0, stream>>>(eidx, lastE);
    count_kernel<<<EE / 256, 256, 0, stream>>>(eidx, lastE, cnt);
    scan2048<<<1, 256, 0, stream>>>(cnt, rowptr, rowoff);
    fill_kernel<<<EE / 256, 256, 0, stream>>>(eidx, lastE, rowoff, csr_dst, csr_eid);
    sort_kernel<<<NN / 256, 256, 0, stream>>>(rowptr, csr_dst, csr_eid);
    gather_kernel<<<EE * 8 / 256, 256, 0, stream>>>(rowptr, csr_eid, eb, csr_b);

    // ---- transformer layers
    for (int d = 0; d < DEPTH; ++d) {
        gemm64<0, 1><<<dim3(HH / 64, NN / 64), 256, 0, stream>>>(h, Wq, bq, nullptr, qb, NN, HH, HH);
        gemm64<0, 1><<<dim3(HH / 64, NN / 64), 256, 0, stream>>>(h, Wk, bk, nullptr, kbf, NN, HH, HH);
        gemm64<0, 2><<<dim3(HH / 64, NN / 64), 256, 0, stream>>>(h, Wv, bv, nullptr, vtb, NN, HH, HH);
        attn_mfma<<<dim3(NHH, NN / 32), 256, 0, stream>>>(qb, kbf, vtb, rowptr, csr_dst, csr_b, ao);
        gemm64<0, 0><<<dim3(HH / 64, NN / 64), 256, 0, stream>>>(ao, Wo, bo, po, nullptr, NN, HH, HH);
        ln_kernel<<<NN / 4, 256, 0, stream>>>(h, po, g1, be1, h);
        gemm64<1, 0><<<dim3(4 * HH / 64, NN / 64), 256, 0, stream>>>(h, W1, b1, ff1, nullptr, NN, 4 * HH, HH);
        gemm64<0, 0><<<dim3(HH / 64, NN / 64), 256, 0, stream>>>(ff1, W2, b2, po, nullptr, NN, HH, 4 * HH);
        float* dst = (d == DEPTH - 1) ? out : h;
        ln_kernel<<<NN / 4, 256, 0, stream>>>(h, po, g2, be2, dst);
    }
    (void)in_sizes; (void)n_in; (void)out_size; (void)ws_size;
}

// Round 3
// 1360.472 us; speedup vs baseline: 7.5397x; 3.5129x over previous
//
#include <hip/hip_runtime.h>
#include <hip/hip_bf16.h>

// Problem constants (fixed shapes)
#define NN 2048      // nodes
#define EE 65536     // edges
#define NF_ 128
#define HH 512
#define NHH 8
#define HD 64
#define DEPTH 5

typedef __attribute__((ext_vector_type(8))) short bf16x8;
typedef __attribute__((ext_vector_type(4))) float f32x4;

__device__ __forceinline__ ushort f2bf(float x) {
    uint u = __builtin_bit_cast(uint, x);
    u += 0x7fffu + ((u >> 16) & 1u);
    return (ushort)(u >> 16);
}

#define GLD16(gp, lp)                                                          \
    __builtin_amdgcn_global_load_lds(                                          \
        (const __attribute__((address_space(1))) unsigned int*)(gp),           \
        (__attribute__((address_space(3))) unsigned int*)(lp), 16, 0, 0)

// ---------------- bf16 MFMA GEMM: C = A[M,K] @ Bt[N,K]^T + bias
// 128 x BN tile, BK=64, 4 waves (2x2), global_load_lds staging, T2 XOR swizzle.
// OUT: 0 = f32 C; 1 = f32 C + bf16 Cb; 2 = bf16 Cb; 3 = qkv scatter (q/k head-major, v transposed)
template<int BN, int OUT, int RELU>
__global__ __launch_bounds__(256) void gemm_mfma(const ushort* __restrict__ A,
                                                 const ushort* __restrict__ Bt,
                                                 const float* __restrict__ bias,
                                                 float* __restrict__ C,
                                                 ushort* __restrict__ Cb,
                                                 ushort* __restrict__ qb,
                                                 ushort* __restrict__ kb,
                                                 ushort* __restrict__ vtb,
                                                 int M, int N, int K) {
    constexpr int WN = BN / 2;
    constexpr int NR = WN / 16;
    __shared__ __align__(16) ushort As[2][128 * 64];
    __shared__ __align__(16) ushort Bs[2][BN * 64];
    const int t = threadIdx.x;
    const int w = t >> 6, l = t & 63;
    const int wr = w >> 1, wc = w & 1;
    const int m0 = blockIdx.y * 128, n0 = blockIdx.x * BN;

    f32x4 acc[4][NR];
#pragma unroll
    for (int m = 0; m < 4; ++m)
#pragma unroll
        for (int n = 0; n < NR; ++n) acc[m][n] = (f32x4){0.f, 0.f, 0.f, 0.f};

    const int srow = t >> 3, sch = t & 7;
    auto stage = [&](int buf, int kt) {
#pragma unroll
        for (int r = 0; r < 4; ++r) {
            int rr = r * 32 + srow;
            int c = sch ^ (rr & 7);                   // inverse swizzle on SOURCE
            GLD16(A + (size_t)(m0 + rr) * K + kt * 64 + c * 8,
                  &As[buf][rr * 64 + sch * 8]);       // linear LDS dest
        }
#pragma unroll
        for (int r = 0; r < BN / 32; ++r) {
            int rr = r * 32 + srow;
            int c = sch ^ (rr & 7);
            GLD16(Bt + (size_t)(n0 + rr) * K + kt * 64 + c * 8,
                  &Bs[buf][rr * 64 + sch * 8]);
        }
    };

    stage(0, 0);
    const int NT = K / 64;
    for (int kt = 0; kt < NT; ++kt) {
        __syncthreads();                              // staged buf[kt&1] ready
        if (kt + 1 < NT) stage((kt + 1) & 1, kt + 1); // prefetch other buffer
        const int buf = kt & 1;
#pragma unroll
        for (int kk = 0; kk < 2; ++kk) {
            bf16x8 af[4], bfr[NR];
#pragma unroll
            for (int m = 0; m < 4; ++m) {
                int R = wr * 64 + m * 16 + (l & 15);
                int c = kk * 4 + (l >> 4);
                af[m] = *(const bf16x8*)&As[buf][R * 64 + (c ^ (R & 7)) * 8];  // swizzled read
            }
#pragma unroll
            for (int n = 0; n < NR; ++n) {
                int R = wc * WN + n * 16 + (l & 15);
                int c = kk * 4 + (l >> 4);
                bfr[n] = *(const bf16x8*)&Bs[buf][R * 64 + (c ^ (R & 7)) * 8];
            }
#pragma unroll
            for (int m = 0; m < 4; ++m)
#pragma unroll
                for (int n = 0; n < NR; ++n)
                    acc[m][n] = __builtin_amdgcn_mfma_f32_16x16x32_bf16(af[m], bfr[n], acc[m][n], 0, 0, 0);
        }
    }

    // epilogue: C/D layout col=l&15, row=(l>>4)*4+j
#pragma unroll
    for (int m = 0; m < 4; ++m) {
        int row = m0 + wr * 64 + m * 16 + (l >> 4) * 4;
#pragma unroll
        for (int n = 0; n < NR; ++n) {
            int col = n0 + wc * WN + n * 16 + (l & 15);
            float bv = bias[col];
#pragma unroll
            for (int j = 0; j < 4; ++j) {
                float vv = acc[m][n][j] + bv;
                if (RELU) vv = fmaxf(vv, 0.f);
                int r = row + j;
                if (OUT == 0) {
                    C[(size_t)r * N + col] = vv;
                } else if (OUT == 1) {
                    C[(size_t)r * N + col] = vv;
                    Cb[(size_t)r * N + col] = f2bf(vv);
                } else if (OUT == 2) {
                    Cb[(size_t)r * N + col] = f2bf(vv);
                } else {
                    int type = col >> 9, head = (col >> 6) & 7, dd = col & 63;
                    ushort bv16 = f2bf(vv);
                    if (type == 0) qb[((size_t)head * NN + r) * 64 + dd] = bv16;
                    else if (type == 1) kb[((size_t)head * NN + r) * 64 + dd] = bv16;
                    else vtb[((size_t)head * 64 + dd) * NN + r] = bv16;
                }
            }
        }
    }
}

// ---------------- setup converts
__global__ __launch_bounds__(256) void xcvt(const float* __restrict__ x, ushort* __restrict__ xb, int n) {
    int i = blockIdx.x * 256 + threadIdx.x;
    if (i < n) xb[i] = f2bf(x[i]);
}

// W[K][N] f32 -> WT[(rowoff+n)][k] bf16 (ldout = K)
__global__ __launch_bounds__(256) void wtrans(const float* __restrict__ W, ushort* __restrict__ WT,
                                              int K, int N, int rowoff) {
    __shared__ float tile[32][33];
    int n0 = blockIdx.x * 32, k0 = blockIdx.y * 32;
    int tc = threadIdx.x & 31, tr = threadIdx.x >> 5;   // 8 rows/pass
#pragma unroll
    for (int i = 0; i < 32; i += 8) tile[tr + i][tc] = W[(size_t)(k0 + tr + i) * N + n0 + tc];
    __syncthreads();
#pragma unroll
    for (int i = 0; i < 32; i += 8)
        WT[(size_t)(rowoff + n0 + tr + i) * K + k0 + tc] = f2bf(tile[tc][tr + i]);
}

__global__ __launch_bounds__(256) void bconcat(const float* __restrict__ a, const float* __restrict__ b,
                                               const float* __restrict__ c, float* __restrict__ o) {
    int i = blockIdx.x * 256 + threadIdx.x;
    if (i < 1536) o[i] = i < 512 ? a[i] : (i < 1024 ? b[i - 512] : c[i - 1024]);
}

// ---------------- e_bias = edge_attr @ We + be   [E,16]x[16,8]
__global__ __launch_bounds__(256) void ebias_kernel(const float* __restrict__ ea,
                                                    const float* __restrict__ We,
                                                    const float* __restrict__ be,
                                                    float* __restrict__ eb) {
    int e = blockIdx.x * 256 + threadIdx.x;
    float a[16];
#pragma unroll
    for (int i = 0; i < 16; ++i) a[i] = ea[(size_t)e * 16 + i];
#pragma unroll
    for (int j = 0; j < 8; ++j) {
        float s = be[j];
#pragma unroll
        for (int i = 0; i < 16; ++i) s += a[i] * We[i * 8 + j];
        eb[(size_t)e * 8 + j] = s;
    }
}

// ---------------- dedupe: last edge index wins per (src,dst)
__global__ __launch_bounds__(256) void amax_kernel(const int* __restrict__ eidx, int* __restrict__ lastE) {
    int e = blockIdx.x * 256 + threadIdx.x;
    int s = eidx[e], d = eidx[EE + e];
    atomicMax(&lastE[s * NN + d], e);
}

__global__ __launch_bounds__(256) void count_kernel(const int* __restrict__ eidx,
                                                    const int* __restrict__ lastE,
                                                    int* __restrict__ cnt) {
    int e = blockIdx.x * 256 + threadIdx.x;
    int s = eidx[e], d = eidx[EE + e];
    if (lastE[s * NN + d] == e) atomicAdd(&cnt[s], 1);
}

__global__ __launch_bounds__(256) void scan2048(const int* __restrict__ cnt,
                                                int* __restrict__ rowptr,
                                                int* __restrict__ rowoff) {
    __shared__ int sums[256];
    int t = threadIdx.x;
    int loc[8];
    int s = 0;
#pragma unroll
    for (int i = 0; i < 8; ++i) { loc[i] = s; s += cnt[t * 8 + i]; }
    sums[t] = s;
    __syncthreads();
    for (int off = 1; off < 256; off <<= 1) {
        int v = (t >= off) ? sums[t - off] : 0;
        __syncthreads();
        sums[t] += v;
        __syncthreads();
    }
    int base = (t == 0) ? 0 : sums[t - 1];
#pragma unroll
    for (int i = 0; i < 8; ++i) { rowptr[t * 8 + i] = base + loc[i]; rowoff[t * 8 + i] = base + loc[i]; }
    if (t == 255) rowptr[NN] = sums[255];
}

__global__ __launch_bounds__(256) void fill_kernel(const int* __restrict__ eidx,
                                                   const int* __restrict__ lastE,
                                                   int* __restrict__ rowoff,
                                                   int* __restrict__ csr_dst,
                                                   int* __restrict__ csr_eid) {
    int e = blockIdx.x * 256 + threadIdx.x;
    int s = eidx[e], d = eidx[EE + e];
    if (lastE[s * NN + d] == e) {
        int pos = atomicAdd(&rowoff[s], 1);
        csr_dst[pos] = d;
        csr_eid[pos] = e;
    }
}

// per-row insertion sort by dst (winners have unique dst -> deterministic result)
__global__ __launch_bounds__(256) void sort_kernel(const int* __restrict__ rowptr,
                                                   int* __restrict__ dst,
                                                   int* __restrict__ eid) {
    int r = blockIdx.x * 256 + threadIdx.x;
    if (r >= NN) return;
    int s = rowptr[r], e = rowptr[r + 1];
    for (int i = s + 1; i < e; ++i) {
        int d = dst[i], id = eid[i];
        int j = i - 1;
        while (j >= s && dst[j] > d) { dst[j + 1] = dst[j]; eid[j + 1] = eid[j]; --j; }
        dst[j + 1] = d; eid[j + 1] = id;
    }
}

__global__ __launch_bounds__(256) void gather_kernel(const int* __restrict__ rowptr,
                                                     const int* __restrict__ eid,
                                                     const float* __restrict__ eb,
                                                     float* __restrict__ csr_b) {
    int idx = blockIdx.x * 256 + threadIdx.x;
    int pos = idx >> 3, j = idx & 7;
    if (pos < rowptr[NN])
        csr_b[(size_t)pos * 8 + j] = eb[(size_t)eid[pos] * 8 + j];
}

// ---------------- one-pass flash attention with MFMA bf16
__global__ __launch_bounds__(256) void attn_mfma(const ushort* __restrict__ qb,
                                                 const ushort* __restrict__ kb,
                                                 const ushort* __restrict__ vtb,
                                                 const int* __restrict__ rowptr,
                                                 const int* __restrict__ csr_dst,
                                                 const float* __restrict__ csr_b,
                                                 ushort* __restrict__ aob) {
    const int head = blockIdx.x;
    const int n0 = blockIdx.y * 32;
    const int t = threadIdx.x;
    const int w = t >> 6, l = t & 63;
    const int mh = w & 1, nh = w >> 1;

    __shared__ __align__(16) ushort Ks[64][72];
    __shared__ __align__(16) ushort Vts[64][72];
    __shared__ __align__(16) float  Sl[32][68];
    __shared__ __align__(16) ushort Pb[32][72];
    __shared__ float Mrow[32], Srow[32], Frow[32];
    __shared__ int   cur[32];

    bf16x8 qf0, qf1;
    {
        int r = n0 + mh * 16 + (l & 15);
        const ushort* qp = qb + ((size_t)head * NN + r) * HD + ((l >> 4) * 8);
        qf0 = *(const bf16x8*)qp;
        qf1 = *(const bf16x8*)(qp + 32);
    }
    if (t < 32) { Mrow[t] = -1e30f; Srow[t] = 0.f; cur[t] = rowptr[n0 + t]; }
    f32x4 o0 = {0.f, 0.f, 0.f, 0.f}, o1 = {0.f, 0.f, 0.f, 0.f};
    __syncthreads();

    for (int m0 = 0; m0 < NN; m0 += 64) {
        {
            const uint* kp = (const uint*)(kb + ((size_t)head * NN + m0) * HD);
            const uint* vp = (const uint*)vtb;
#pragma unroll
            for (int i = t; i < 2048; i += 256) {
                int r = i >> 5, c = i & 31;
                ((uint*)&Ks[r][0])[c] = kp[r * 32 + c];
                ((uint*)&Vts[r][0])[c] = vp[(((size_t)head * HD + r) * NN + m0) / 2 + c];
            }
        }
        __syncthreads();
        {
            int dimb = (l >> 4) * 8;
            int key0 = nh * 32 + (l & 15);
            bf16x8 ka0 = *(const bf16x8*)&Ks[key0][dimb];
            bf16x8 ka1 = *(const bf16x8*)&Ks[key0][dimb + 32];
            bf16x8 kb0 = *(const bf16x8*)&Ks[key0 + 16][dimb];
            bf16x8 kb1 = *(const bf16x8*)&Ks[key0 + 16][dimb + 32];
            f32x4 s0 = {0.f, 0.f, 0.f, 0.f}, s1 = {0.f, 0.f, 0.f, 0.f};
            s0 = __builtin_amdgcn_mfma_f32_16x16x32_bf16(qf0, ka0, s0, 0, 0, 0);
            s0 = __builtin_amdgcn_mfma_f32_16x16x32_bf16(qf1, ka1, s0, 0, 0, 0);
            s1 = __builtin_amdgcn_mfma_f32_16x16x32_bf16(qf0, kb0, s1, 0, 0, 0);
            s1 = __builtin_amdgcn_mfma_f32_16x16x32_bf16(qf1, kb1, s1, 0, 0, 0);
            int row = mh * 16 + (l >> 4) * 4;
            int c0 = nh * 32 + (l & 15);
#pragma unroll
            for (int j = 0; j < 4; ++j) {
                Sl[row + j][c0] = s0[j] * 0.125f;
                Sl[row + j][c0 + 16] = s1[j] * 0.125f;
            }
        }
        __syncthreads();
        if (t < 32) {
            int c = cur[t], end = rowptr[n0 + t + 1];
            int lim = m0 + 64;
            while (c < end) {
                int dd = csr_dst[c];
                if (dd >= lim) break;
                Sl[t][dd - m0] += csr_b[(size_t)c * 8 + head];
                ++c;
            }
            cur[t] = c;
        }
        __syncthreads();
        {
            int r = t >> 3, j = t & 7;
            f32x4 a = *(const f32x4*)&Sl[r][j * 8];
            f32x4 b = *(const f32x4*)&Sl[r][j * 8 + 4];
            float tm = fmaxf(fmaxf(fmaxf(a[0], a[1]), fmaxf(a[2], a[3])),
                             fmaxf(fmaxf(b[0], b[1]), fmaxf(b[2], b[3])));
            tm = fmaxf(tm, __shfl_xor(tm, 1, 64));
            tm = fmaxf(tm, __shfl_xor(tm, 2, 64));
            tm = fmaxf(tm, __shfl_xor(tm, 4, 64));
            float Mo = Mrow[r];
            float Mn = fmaxf(Mo, tm);
            float p[8];
#pragma unroll
            for (int i = 0; i < 4; ++i) p[i] = __expf(a[i] - Mn);
#pragma unroll
            for (int i = 0; i < 4; ++i) p[4 + i] = __expf(b[i] - Mn);
            float ts = 0.f;
#pragma unroll
            for (int i = 0; i < 8; ++i) ts += p[i];
            ts += __shfl_xor(ts, 1, 64);
            ts += __shfl_xor(ts, 2, 64);
            ts += __shfl_xor(ts, 4, 64);
            int4 pk;
            pk.x = (int)((uint)f2bf(p[0]) | ((uint)f2bf(p[1]) << 16));
            pk.y = (int)((uint)f2bf(p[2]) | ((uint)f2bf(p[3]) << 16));
            pk.z = (int)((uint)f2bf(p[4]) | ((uint)f2bf(p[5]) << 16));
            pk.w = (int)((uint)f2bf(p[6]) | ((uint)f2bf(p[7]) << 16));
            *(int4*)&Pb[r][j * 8] = pk;
            if (j == 0) {
                float f = __expf(Mo - Mn);
                Mrow[r] = Mn;
                Srow[r] = Srow[r] * f + ts;
                Frow[r] = f;
            }
        }
        __syncthreads();
        {
            int row4 = mh * 16 + (l >> 4) * 4;
#pragma unroll
            for (int j = 0; j < 4; ++j) {
                float fj = Frow[row4 + j];
                o0[j] *= fj;
                o1[j] *= fj;
            }
            int kbase = (l >> 4) * 8;
            int prow = mh * 16 + (l & 15);
            bf16x8 p0 = *(const bf16x8*)&Pb[prow][kbase];
            bf16x8 p1 = *(const bf16x8*)&Pb[prow][kbase + 32];
            int d0 = nh * 32 + (l & 15);
            bf16x8 v00 = *(const bf16x8*)&Vts[d0][kbase];
            bf16x8 v01 = *(const bf16x8*)&Vts[d0][kbase + 32];
            bf16x8 v10 = *(const bf16x8*)&Vts[d0 + 16][kbase];
            bf16x8 v11 = *(const bf16x8*)&Vts[d0 + 16][kbase + 32];
            o0 = __builtin_amdgcn_mfma_f32_16x16x32_bf16(p0, v00, o0, 0, 0, 0);
            o0 = __builtin_amdgcn_mfma_f32_16x16x32_bf16(p1, v01, o0, 0, 0, 0);
            o1 = __builtin_amdgcn_mfma_f32_16x16x32_bf16(p0, v10, o1, 0, 0, 0);
            o1 = __builtin_amdgcn_mfma_f32_16x16x32_bf16(p1, v11, o1, 0, 0, 0);
        }
        __syncthreads();
    }
    {
        int row4 = mh * 16 + (l >> 4) * 4;
        int c0 = nh * 32 + (l & 15);
#pragma unroll
        for (int j = 0; j < 4; ++j) {
            int r = row4 + j;
            float inv = 1.f / Srow[r];
            ushort* dst = aob + (size_t)(n0 + r) * HH + head * HD;
            dst[c0] = f2bf(o0[j] * inv);
            dst[c0 + 16] = f2bf(o1[j] * inv);
        }
    }
}

// ---------------- LayerNorm(out = LN(a + b) * g + be), rows of 512; optional bf16 copy
template<int BF16OUT>
__global__ __launch_bounds__(256) void ln_kernel(const float* __restrict__ a,
                                                 const float* __restrict__ b,
                                                 const float* __restrict__ g,
                                                 const float* __restrict__ be,
                                                 float* __restrict__ out,
                                                 ushort* __restrict__ outb) {
    int row = blockIdx.x * 4 + (threadIdx.x >> 6);
    int lane = threadIdx.x & 63;
    const float* pa = a + (size_t)row * HH;
    const float* pb = b + (size_t)row * HH;
    float x[8];
    float s = 0.f;
#pragma unroll
    for (int i = 0; i < 8; ++i) { x[i] = pa[lane + i * 64] + pb[lane + i * 64]; s += x[i]; }
#pragma unroll
    for (int off = 32; off > 0; off >>= 1) s += __shfl_xor(s, off, 64);
    float mean = s * (1.f / 512.f);
    float vs = 0.f;
#pragma unroll
    for (int i = 0; i < 8; ++i) { float d = x[i] - mean; vs += d * d; }
#pragma unroll
    for (int off = 32; off > 0; off >>= 1) vs += __shfl_xor(vs, off, 64);
    float rs = rsqrtf(vs * (1.f / 512.f) + 1e-5f);
    float* po = out + (size_t)row * HH;
    ushort* pob = outb + (size_t)row * HH;
#pragma unroll
    for (int i = 0; i < 8; ++i) {
        float v = (x[i] - mean) * rs * g[lane + i * 64] + be[lane + i * 64];
        po[lane + i * 64] = v;
        if (BF16OUT) pob[lane + i * 64] = f2bf(v);
    }
}

extern "C" void kernel_launch(void* const* d_in, const int* in_sizes, int n_in,
                              void* d_out, int out_size, void* d_ws, size_t ws_size,
                              hipStream_t stream) {
    const float* x   = (const float*)d_in[0];
    const int*  eidx = (const int*)d_in[1];
    const float* ea  = (const float*)d_in[2];
    const float* Wn = (const float*)d_in[3];  const float* bn = (const float*)d_in[4];
    const float* We = (const float*)d_in[5];  const float* be = (const float*)d_in[6];
    const float* Wq = (const float*)d_in[7];  const float* bq = (const float*)d_in[8];
    const float* Wk = (const float*)d_in[9];  const float* bk = (const float*)d_in[10];
    const float* Wv = (const float*)d_in[11]; const float* bv = (const float*)d_in[12];
    const float* Wo = (const float*)d_in[13]; const float* bo = (const float*)d_in[14];
    const float* W1 = (const float*)d_in[15]; const float* b1 = (const float*)d_in[16];
    const float* W2 = (const float*)d_in[17]; const float* b2 = (const float*)d_in[18];
    const float* g1 = (const float*)d_in[19]; const float* be1 = (const float*)d_in[20];
    const float* g2 = (const float*)d_in[21]; const float* be2 = (const float*)d_in[22];
    float* out = (float*)d_out;

    // workspace carve (bytes, 256-aligned)
    char* base = (char*)d_ws;
    size_t off = 0;
    auto carve = [&](size_t bytes) { void* p = base + off; off = (off + bytes + 255) & ~(size_t)255; return p; };
    float*  h    = (float*)carve((size_t)NN * HH * 4);
    ushort* hb   = (ushort*)carve((size_t)NN * HH * 2);
    // [po, ff1b, qb, kbf] are contiguous 16 MB -> aliased as lastE during setup
    float*  po   = (float*)carve((size_t)NN * HH * 4);
    ushort* ff1b = (ushort*)carve((size_t)NN * 4 * HH * 2);
    ushort* qb   = (ushort*)carve((size_t)NN * HH * 2);
    ushort* kbf  = (ushort*)carve((size_t)NN * HH * 2);
    ushort* vtb  = (ushort*)carve((size_t)NN * HH * 2);
    ushort* aob  = (ushort*)carve((size_t)NN * HH * 2);
    ushort* xb   = (ushort*)carve((size_t)NN * NF_ * 2);
    ushort* WnT  = (ushort*)carve((size_t)HH * NF_ * 2);
    ushort* WqkvT= (ushort*)carve((size_t)3 * HH * HH * 2);
    ushort* WoT  = (ushort*)carve((size_t)HH * HH * 2);
    ushort* W1T  = (ushort*)carve((size_t)4 * HH * HH * 2);
    ushort* W2T  = (ushort*)carve((size_t)4 * HH * HH * 2);
    float*  bqkv = (float*)carve((size_t)3 * HH * 4);
    float*  eb   = (float*)carve((size_t)EE * NHH * 4);
    float*  csr_b= (float*)carve((size_t)EE * NHH * 4);
    int* cnt     = (int*)carve((size_t)NN * 4);
    int* rowptr  = (int*)carve((size_t)(NN + 1) * 4);
    int* rowoff  = (int*)carve((size_t)NN * 4);
    int* csr_dst = (int*)carve((size_t)EE * 4);
    int* csr_eid = (int*)carve((size_t)EE * 4);
    int* lastE = (int*)po;  // setup alias: po+ff1b+qb+kbf = 4+8+2+2 MB = 16 MB = NN*NN*4

    // ---- setup
    hipMemsetAsync(lastE, 0xFF, (size_t)NN * NN * 4, stream);   // -1
    hipMemsetAsync(cnt, 0, (size_t)NN * 4, stream);

    xcvt<<<(NN * NF_ + 255) / 256, 256, 0, stream>>>(x, xb, NN * NF_);
    wtrans<<<dim3(HH / 32, NF_ / 32), 256, 0, stream>>>(Wn, WnT, NF_, HH, 0);
    wtrans<<<dim3(HH / 32, HH / 32), 256, 0, stream>>>(Wq, WqkvT, HH, HH, 0);
    wtrans<<<dim3(HH / 32, HH / 32), 256, 0, stream>>>(Wk, WqkvT, HH, HH, 512);
    wtrans<<<dim3(HH / 32, HH / 32), 256, 0, stream>>>(Wv, WqkvT, HH, HH, 1024);
    wtrans<<<dim3(HH / 32, HH / 32), 256, 0, stream>>>(Wo, WoT, HH, HH, 0);
    wtrans<<<dim3(4 * HH / 32, HH / 32), 256, 0, stream>>>(W1, W1T, HH, 4 * HH, 0);
    wtrans<<<dim3(HH / 32, 4 * HH / 32), 256, 0, stream>>>(W2, W2T, 4 * HH, HH, 0);
    bconcat<<<6, 256, 0, stream>>>(bq, bk, bv, bqkv);

    ebias_kernel<<<EE / 256, 256, 0, stream>>>(ea, We, be, eb);
    amax_kernel<<<EE / 256, 256, 0, stream>>>(eidx, lastE);
    count_kernel<<<EE / 256, 256, 0, stream>>>(eidx, lastE, cnt);
    scan2048<<<1, 256, 0, stream>>>(cnt, rowptr, rowoff);
    fill_kernel<<<EE / 256, 256, 0, stream>>>(eidx, lastE, rowoff, csr_dst, csr_eid);
    sort_kernel<<<NN / 256, 256, 0, stream>>>(rowptr, csr_dst, csr_eid);
    gather_kernel<<<EE * 8 / 256, 256, 0, stream>>>(rowptr, csr_eid, eb, csr_b);

    // h = x @ Wn + bn  (f32 + bf16)
    gemm_mfma<64, 1, 0><<<dim3(HH / 64, NN / 128), 256, 0, stream>>>(
        xb, WnT, bn, h, hb, nullptr, nullptr, nullptr, NN, HH, NF_);

    // ---- transformer layers
    for (int d = 0; d < DEPTH; ++d) {
        gemm_mfma<128, 3, 0><<<dim3(3 * HH / 128, NN / 128), 256, 0, stream>>>(
            hb, WqkvT, bqkv, nullptr, nullptr, qb, kbf, vtb, NN, 3 * HH, HH);
        attn_mfma<<<dim3(NHH, NN / 32), 256, 0, stream>>>(qb, kbf, vtb, rowptr, csr_dst, csr_b, aob);
        gemm_mfma<64, 0, 0><<<dim3(HH / 64, NN / 128), 256, 0, stream>>>(
            aob, WoT, bo, po, nullptr, nullptr, nullptr, nullptr, NN, HH, HH);
        ln_kernel<1><<<NN / 4, 256, 0, stream>>>(h, po, g1, be1, h, hb);
        gemm_mfma<128, 2, 1><<<dim3(4 * HH / 128, NN / 128), 256, 0, stream>>>(
            hb, W1T, b1, nullptr, ff1b, nullptr, nullptr, nullptr, NN, 4 * HH, HH);
        gemm_mfma<64, 0, 0><<<dim3(HH / 64, NN / 128), 256, 0, stream>>>(
            ff1b, W2T, b2, po, nullptr, nullptr, nullptr, nullptr, NN, HH, 4 * HH);
        float* dst = (d == DEPTH - 1) ? out : h;
        ln_kernel<1><<<NN / 4, 256, 0, stream>>>(h, po, g2, be2, dst, hb);
    }
    (void)in_sizes; (void)n_in; (void)out_size; (void)ws_size;
}

// Round 4
// 1055.608 us; speedup vs baseline: 9.7171x; 1.2888x over previous
//
#include <hip/hip_runtime.h>
#include <hip/hip_bf16.h>

// Problem constants (fixed shapes)
#define NN 2048      // nodes
#define EE 65536     // edges
#define NF_ 128
#define HH 512
#define NHH 8
#define HD 64
#define DEPTH 5

typedef __attribute__((ext_vector_type(8))) short bf16x8;
typedef __attribute__((ext_vector_type(4))) float f32x4;

__device__ __forceinline__ ushort f2bf(float x) {
    uint u = __builtin_bit_cast(uint, x);
    u += 0x7fffu + ((u >> 16) & 1u);
    return (ushort)(u >> 16);
}

#define GLD16(gp, lp)                                                          \
    __builtin_amdgcn_global_load_lds(                                          \
        (const __attribute__((address_space(1))) unsigned int*)(gp),           \
        (__attribute__((address_space(3))) unsigned int*)(lp), 16, 0, 0)

// ---------------- bf16 MFMA GEMM: C = A[M,K] @ Bt[N,K]^T + bias
// 128 x BN tile, BK=64, 4 waves (2x2), global_load_lds staging, T2 XOR swizzle.
// OUT: 0 = f32 C; 1 = f32 C + bf16 Cb; 2 = bf16 Cb; 3 = qkv scatter (q/k head-major, v transposed)
template<int BN, int OUT, int RELU>
__global__ __launch_bounds__(256) void gemm_mfma(const ushort* __restrict__ A,
                                                 const ushort* __restrict__ Bt,
                                                 const float* __restrict__ bias,
                                                 float* __restrict__ C,
                                                 ushort* __restrict__ Cb,
                                                 ushort* __restrict__ qb,
                                                 ushort* __restrict__ kb,
                                                 ushort* __restrict__ vtb,
                                                 int M, int N, int K) {
    constexpr int WN = BN / 2;
    constexpr int NR = WN / 16;
    __shared__ __align__(16) ushort As[2][128 * 64];
    __shared__ __align__(16) ushort Bs[2][BN * 64];
    const int t = threadIdx.x;
    const int w = t >> 6, l = t & 63;
    const int wr = w >> 1, wc = w & 1;
    const int m0 = blockIdx.y * 128, n0 = blockIdx.x * BN;

    f32x4 acc[4][NR];
#pragma unroll
    for (int m = 0; m < 4; ++m)
#pragma unroll
        for (int n = 0; n < NR; ++n) acc[m][n] = (f32x4){0.f, 0.f, 0.f, 0.f};

    const int srow = t >> 3, sch = t & 7;
    auto stage = [&](int buf, int kt) {
#pragma unroll
        for (int r = 0; r < 4; ++r) {
            int rr = r * 32 + srow;
            int c = sch ^ (rr & 7);                   // inverse swizzle on SOURCE
            GLD16(A + (size_t)(m0 + rr) * K + kt * 64 + c * 8,
                  &As[buf][rr * 64 + sch * 8]);       // linear LDS dest
        }
#pragma unroll
        for (int r = 0; r < BN / 32; ++r) {
            int rr = r * 32 + srow;
            int c = sch ^ (rr & 7);
            GLD16(Bt + (size_t)(n0 + rr) * K + kt * 64 + c * 8,
                  &Bs[buf][rr * 64 + sch * 8]);
        }
    };

    stage(0, 0);
    const int NT = K / 64;
    for (int kt = 0; kt < NT; ++kt) {
        __syncthreads();                              // staged buf[kt&1] ready
        if (kt + 1 < NT) stage((kt + 1) & 1, kt + 1); // prefetch other buffer
        const int buf = kt & 1;
#pragma unroll
        for (int kk = 0; kk < 2; ++kk) {
            bf16x8 af[4], bfr[NR];
#pragma unroll
            for (int m = 0; m < 4; ++m) {
                int R = wr * 64 + m * 16 + (l & 15);
                int c = kk * 4 + (l >> 4);
                af[m] = *(const bf16x8*)&As[buf][R * 64 + (c ^ (R & 7)) * 8];  // swizzled read
            }
#pragma unroll
            for (int n = 0; n < NR; ++n) {
                int R = wc * WN + n * 16 + (l & 15);
                int c = kk * 4 + (l >> 4);
                bfr[n] = *(const bf16x8*)&Bs[buf][R * 64 + (c ^ (R & 7)) * 8];
            }
#pragma unroll
            for (int m = 0; m < 4; ++m)
#pragma unroll
                for (int n = 0; n < NR; ++n)
                    acc[m][n] = __builtin_amdgcn_mfma_f32_16x16x32_bf16(af[m], bfr[n], acc[m][n], 0, 0, 0);
        }
    }

    // epilogue: C/D layout col=l&15, row=(l>>4)*4+j
#pragma unroll
    for (int m = 0; m < 4; ++m) {
        int row = m0 + wr * 64 + m * 16 + (l >> 4) * 4;
#pragma unroll
        for (int n = 0; n < NR; ++n) {
            int col = n0 + wc * WN + n * 16 + (l & 15);
            float bv = bias[col];
#pragma unroll
            for (int j = 0; j < 4; ++j) {
                float vv = acc[m][n][j] + bv;
                if (RELU) vv = fmaxf(vv, 0.f);
                int r = row + j;
                if (OUT == 0) {
                    C[(size_t)r * N + col] = vv;
                } else if (OUT == 1) {
                    C[(size_t)r * N + col] = vv;
                    Cb[(size_t)r * N + col] = f2bf(vv);
                } else if (OUT == 2) {
                    Cb[(size_t)r * N + col] = f2bf(vv);
                } else {
                    int type = col >> 9, head = (col >> 6) & 7, dd = col & 63;
                    ushort bv16 = f2bf(vv);
                    if (type == 0) qb[((size_t)head * NN + r) * 64 + dd] = bv16;
                    else if (type == 1) kb[((size_t)head * NN + r) * 64 + dd] = bv16;
                    else vtb[((size_t)head * 64 + dd) * NN + r] = bv16;
                }
            }
        }
    }
}

// ---------------- setup converts
__global__ __launch_bounds__(256) void xcvt(const float* __restrict__ x, ushort* __restrict__ xb, int n) {
    int i = blockIdx.x * 256 + threadIdx.x;
    if (i < n) xb[i] = f2bf(x[i]);
}

// W[K][N] f32 -> WT[(rowoff+n)][k] bf16 (ldout = K)
__global__ __launch_bounds__(256) void wtrans(const float* __restrict__ W, ushort* __restrict__ WT,
                                              int K, int N, int rowoff) {
    __shared__ float tile[32][33];
    int n0 = blockIdx.x * 32, k0 = blockIdx.y * 32;
    int tc = threadIdx.x & 31, tr = threadIdx.x >> 5;   // 8 rows/pass
#pragma unroll
    for (int i = 0; i < 32; i += 8) tile[tr + i][tc] = W[(size_t)(k0 + tr + i) * N + n0 + tc];
    __syncthreads();
#pragma unroll
    for (int i = 0; i < 32; i += 8)
        WT[(size_t)(rowoff + n0 + tr + i) * K + k0 + tc] = f2bf(tile[tc][tr + i]);
}

__global__ __launch_bounds__(256) void bconcat(const float* __restrict__ a, const float* __restrict__ b,
                                               const float* __restrict__ c, float* __restrict__ o) {
    int i = blockIdx.x * 256 + threadIdx.x;
    if (i < 1536) o[i] = i < 512 ? a[i] : (i < 1024 ? b[i - 512] : c[i - 1024]);
}

// ---------------- e_bias = edge_attr @ We + be   [E,16]x[16,8]
__global__ __launch_bounds__(256) void ebias_kernel(const float* __restrict__ ea,
                                                    const float* __restrict__ We,
                                                    const float* __restrict__ be,
                                                    float* __restrict__ eb) {
    int e = blockIdx.x * 256 + threadIdx.x;
    float a[16];
#pragma unroll
    for (int i = 0; i < 16; ++i) a[i] = ea[(size_t)e * 16 + i];
#pragma unroll
    for (int j = 0; j < 8; ++j) {
        float s = be[j];
#pragma unroll
        for (int i = 0; i < 16; ++i) s += a[i] * We[i * 8 + j];
        eb[(size_t)e * 8 + j] = s;
    }
}

// ---------------- dedupe: last edge index wins per (src,dst)
__global__ __launch_bounds__(256) void amax_kernel(const int* __restrict__ eidx, int* __restrict__ lastE) {
    int e = blockIdx.x * 256 + threadIdx.x;
    int s = eidx[e], d = eidx[EE + e];
    atomicMax(&lastE[s * NN + d], e);
}

__global__ __launch_bounds__(256) void count_kernel(const int* __restrict__ eidx,
                                                    const int* __restrict__ lastE,
                                                    int* __restrict__ cnt) {
    int e = blockIdx.x * 256 + threadIdx.x;
    int s = eidx[e], d = eidx[EE + e];
    if (lastE[s * NN + d] == e) atomicAdd(&cnt[s], 1);
}

__global__ __launch_bounds__(256) void scan2048(const int* __restrict__ cnt,
                                                int* __restrict__ rowptr,
                                                int* __restrict__ rowoff) {
    __shared__ int sums[256];
    int t = threadIdx.x;
    int loc[8];
    int s = 0;
#pragma unroll
    for (int i = 0; i < 8; ++i) { loc[i] = s; s += cnt[t * 8 + i]; }
    sums[t] = s;
    __syncthreads();
    for (int off = 1; off < 256; off <<= 1) {
        int v = (t >= off) ? sums[t - off] : 0;
        __syncthreads();
        sums[t] += v;
        __syncthreads();
    }
    int base = (t == 0) ? 0 : sums[t - 1];
#pragma unroll
    for (int i = 0; i < 8; ++i) { rowptr[t * 8 + i] = base + loc[i]; rowoff[t * 8 + i] = base + loc[i]; }
    if (t == 255) rowptr[NN] = sums[255];
}

// fill CSR directly (unsorted within a row; winners have unique (src,dst) so
// each slot is written once -> deterministic attention result)
__global__ __launch_bounds__(256) void fill_kernel(const int* __restrict__ eidx,
                                                   const int* __restrict__ lastE,
                                                   const float* __restrict__ eb,
                                                   int* __restrict__ rowoff,
                                                   int* __restrict__ csr_dst,
                                                   float* __restrict__ csr_b) {
    int e = blockIdx.x * 256 + threadIdx.x;
    int s = eidx[e], d = eidx[EE + e];
    if (lastE[s * NN + d] == e) {
        int pos = atomicAdd(&rowoff[s], 1);
        csr_dst[pos] = d;
#pragma unroll
        for (int j = 0; j < 8; ++j) csr_b[(size_t)pos * 8 + j] = eb[(size_t)e * 8 + j];
    }
}

// ---------------- one-pass flash attention with MFMA bf16
__global__ __launch_bounds__(256) void attn_mfma(const ushort* __restrict__ qb,
                                                 const ushort* __restrict__ kb,
                                                 const ushort* __restrict__ vtb,
                                                 const int* __restrict__ rowptr,
                                                 const int* __restrict__ csr_dst,
                                                 const float* __restrict__ csr_b,
                                                 ushort* __restrict__ aob) {
    const int head = blockIdx.x;
    const int n0 = blockIdx.y * 32;
    const int t = threadIdx.x;
    const int w = t >> 6, l = t & 63;
    const int mh = w & 1, nh = w >> 1;

    __shared__ __align__(16) ushort Ks[64][72];
    __shared__ __align__(16) ushort Vts[64][72];
    __shared__ __align__(16) float  Sl[32][68];
    __shared__ __align__(16) ushort Pb[32][72];
    __shared__ float Mrow[32], Srow[32], Frow[32];

    bf16x8 qf0, qf1;
    {
        int r = n0 + mh * 16 + (l & 15);
        const ushort* qp = qb + ((size_t)head * NN + r) * HD + ((l >> 4) * 8);
        qf0 = *(const bf16x8*)qp;
        qf1 = *(const bf16x8*)(qp + 32);
    }
    if (t < 32) { Mrow[t] = -1e30f; Srow[t] = 0.f; }
    // bias-scatter assignment: 8 threads per row, row's CSR range in registers
    const int brow = t >> 3, bj = t & 7;
    const int be0 = rowptr[n0 + brow], be1 = rowptr[n0 + brow + 1];
    f32x4 o0 = {0.f, 0.f, 0.f, 0.f}, o1 = {0.f, 0.f, 0.f, 0.f};
    __syncthreads();

    for (int m0 = 0; m0 < NN; m0 += 64) {
        {
            const uint* kp = (const uint*)(kb + ((size_t)head * NN + m0) * HD);
            const uint* vp = (const uint*)vtb;
#pragma unroll
            for (int i = t; i < 2048; i += 256) {
                int r = i >> 5, c = i & 31;
                ((uint*)&Ks[r][0])[c] = kp[r * 32 + c];
                ((uint*)&Vts[r][0])[c] = vp[(((size_t)head * HD + r) * NN + m0) / 2 + c];
            }
        }
        __syncthreads();
        {
            int dimb = (l >> 4) * 8;
            int key0 = nh * 32 + (l & 15);
            bf16x8 ka0 = *(const bf16x8*)&Ks[key0][dimb];
            bf16x8 ka1 = *(const bf16x8*)&Ks[key0][dimb + 32];
            bf16x8 kb0 = *(const bf16x8*)&Ks[key0 + 16][dimb];
            bf16x8 kb1 = *(const bf16x8*)&Ks[key0 + 16][dimb + 32];
            f32x4 s0 = {0.f, 0.f, 0.f, 0.f}, s1 = {0.f, 0.f, 0.f, 0.f};
            s0 = __builtin_amdgcn_mfma_f32_16x16x32_bf16(qf0, ka0, s0, 0, 0, 0);
            s0 = __builtin_amdgcn_mfma_f32_16x16x32_bf16(qf1, ka1, s0, 0, 0, 0);
            s1 = __builtin_amdgcn_mfma_f32_16x16x32_bf16(qf0, kb0, s1, 0, 0, 0);
            s1 = __builtin_amdgcn_mfma_f32_16x16x32_bf16(qf1, kb1, s1, 0, 0, 0);
            int row = mh * 16 + (l >> 4) * 4;
            int c0 = nh * 32 + (l & 15);
#pragma unroll
            for (int j = 0; j < 4; ++j) {
                Sl[row + j][c0] = s0[j] * 0.125f;
                Sl[row + j][c0 + 16] = s1[j] * 0.125f;
            }
        }
        __syncthreads();
        {   // sparse bias scatter: full-row scan with tile range check (unsorted CSR)
            for (int e = be0 + bj; e < be1; e += 8) {
                unsigned dd = (unsigned)(csr_dst[e] - m0);
                if (dd < 64u) Sl[brow][dd] += csr_b[(size_t)e * 8 + head];
            }
        }
        __syncthreads();
        {
            int r = t >> 3, j = t & 7;
            f32x4 a = *(const f32x4*)&Sl[r][j * 8];
            f32x4 b = *(const f32x4*)&Sl[r][j * 8 + 4];
            float tm = fmaxf(fmaxf(fmaxf(a[0], a[1]), fmaxf(a[2], a[3])),
                             fmaxf(fmaxf(b[0], b[1]), fmaxf(b[2], b[3])));
            tm = fmaxf(tm, __shfl_xor(tm, 1, 64));
            tm = fmaxf(tm, __shfl_xor(tm, 2, 64));
            tm = fmaxf(tm, __shfl_xor(tm, 4, 64));
            float Mo = Mrow[r];
            float Mn = fmaxf(Mo, tm);
            float p[8];
#pragma unroll
            for (int i = 0; i < 4; ++i) p[i] = __expf(a[i] - Mn);
#pragma unroll
            for (int i = 0; i < 4; ++i) p[4 + i] = __expf(b[i] - Mn);
            float ts = 0.f;
#pragma unroll
            for (int i = 0; i < 8; ++i) ts += p[i];
            ts += __shfl_xor(ts, 1, 64);
            ts += __shfl_xor(ts, 2, 64);
            ts += __shfl_xor(ts, 4, 64);
            int4 pk;
            pk.x = (int)((uint)f2bf(p[0]) | ((uint)f2bf(p[1]) << 16));
            pk.y = (int)((uint)f2bf(p[2]) | ((uint)f2bf(p[3]) << 16));
            pk.z = (int)((uint)f2bf(p[4]) | ((uint)f2bf(p[5]) << 16));
            pk.w = (int)((uint)f2bf(p[6]) | ((uint)f2bf(p[7]) << 16));
            *(int4*)&Pb[r][j * 8] = pk;
            if (j == 0) {
                float f = __expf(Mo - Mn);
                Mrow[r] = Mn;
                Srow[r] = Srow[r] * f + ts;
                Frow[r] = f;
            }
        }
        __syncthreads();
        {
            int row4 = mh * 16 + (l >> 4) * 4;
#pragma unroll
            for (int j = 0; j < 4; ++j) {
                float fj = Frow[row4 + j];
                o0[j] *= fj;
                o1[j] *= fj;
            }
            int kbase = (l >> 4) * 8;
            int prow = mh * 16 + (l & 15);
            bf16x8 p0 = *(const bf16x8*)&Pb[prow][kbase];
            bf16x8 p1 = *(const bf16x8*)&Pb[prow][kbase + 32];
            int d0 = nh * 32 + (l & 15);
            bf16x8 v00 = *(const bf16x8*)&Vts[d0][kbase];
            bf16x8 v01 = *(const bf16x8*)&Vts[d0][kbase + 32];
            bf16x8 v10 = *(const bf16x8*)&Vts[d0 + 16][kbase];
            bf16x8 v11 = *(const bf16x8*)&Vts[d0 + 16][kbase + 32];
            o0 = __builtin_amdgcn_mfma_f32_16x16x32_bf16(p0, v00, o0, 0, 0, 0);
            o0 = __builtin_amdgcn_mfma_f32_16x16x32_bf16(p1, v01, o0, 0, 0, 0);
            o1 = __builtin_amdgcn_mfma_f32_16x16x32_bf16(p0, v10, o1, 0, 0, 0);
            o1 = __builtin_amdgcn_mfma_f32_16x16x32_bf16(p1, v11, o1, 0, 0, 0);
        }
        __syncthreads();
    }
    {
        int row4 = mh * 16 + (l >> 4) * 4;
        int c0 = nh * 32 + (l & 15);
#pragma unroll
        for (int j = 0; j < 4; ++j) {
            int r = row4 + j;
            float inv = 1.f / Srow[r];
            ushort* dst = aob + (size_t)(n0 + r) * HH + head * HD;
            dst[c0] = f2bf(o0[j] * inv);
            dst[c0 + 16] = f2bf(o1[j] * inv);
        }
    }
}

// ---------------- LayerNorm(out = LN(a + b) * g + be), rows of 512; optional bf16 copy
template<int BF16OUT>
__global__ __launch_bounds__(256) void ln_kernel(const float* __restrict__ a,
                                                 const float* __restrict__ b,
                                                 const float* __restrict__ g,
                                                 const float* __restrict__ be,
                                                 float* __restrict__ out,
                                                 ushort* __restrict__ outb) {
    int row = blockIdx.x * 4 + (threadIdx.x >> 6);
    int lane = threadIdx.x & 63;
    const float* pa = a + (size_t)row * HH;
    const float* pb = b + (size_t)row * HH;
    float x[8];
    float s = 0.f;
#pragma unroll
    for (int i = 0; i < 8; ++i) { x[i] = pa[lane + i * 64] + pb[lane + i * 64]; s += x[i]; }
#pragma unroll
    for (int off = 32; off > 0; off >>= 1) s += __shfl_xor(s, off, 64);
    float mean = s * (1.f / 512.f);
    float vs = 0.f;
#pragma unroll
    for (int i = 0; i < 8; ++i) { float d = x[i] - mean; vs += d * d; }
#pragma unroll
    for (int off = 32; off > 0; off >>= 1) vs += __shfl_xor(vs, off, 64);
    float rs = rsqrtf(vs * (1.f / 512.f) + 1e-5f);
    float* po = out + (size_t)row * HH;
    ushort* pob = outb + (size_t)row * HH;
#pragma unroll
    for (int i = 0; i < 8; ++i) {
        float v = (x[i] - mean) * rs * g[lane + i * 64] + be[lane + i * 64];
        po[lane + i * 64] = v;
        if (BF16OUT) pob[lane + i * 64] = f2bf(v);
    }
}

extern "C" void kernel_launch(void* const* d_in, const int* in_sizes, int n_in,
                              void* d_out, int out_size, void* d_ws, size_t ws_size,
                              hipStream_t stream) {
    const float* x   = (const float*)d_in[0];
    const int*  eidx = (const int*)d_in[1];
    const float* ea  = (const float*)d_in[2];
    const float* Wn = (const float*)d_in[3];  const float* bn = (const float*)d_in[4];
    const float* We = (const float*)d_in[5];  const float* be = (const float*)d_in[6];
    const float* Wq = (const float*)d_in[7];  const float* bq = (const float*)d_in[8];
    const float* Wk = (const float*)d_in[9];  const float* bk = (const float*)d_in[10];
    const float* Wv = (const float*)d_in[11]; const float* bv = (const float*)d_in[12];
    const float* Wo = (const float*)d_in[13]; const float* bo = (const float*)d_in[14];
    const float* W1 = (const float*)d_in[15]; const float* b1 = (const float*)d_in[16];
    const float* W2 = (const float*)d_in[17]; const float* b2 = (const float*)d_in[18];
    const float* g1 = (const float*)d_in[19]; const float* be1 = (const float*)d_in[20];
    const float* g2 = (const float*)d_in[21]; const float* be2 = (const float*)d_in[22];
    float* out = (float*)d_out;

    // workspace carve (bytes, 256-aligned)
    char* base = (char*)d_ws;
    size_t off = 0;
    auto carve = [&](size_t bytes) { void* p = base + off; off = (off + bytes + 255) & ~(size_t)255; return p; };
    float*  h    = (float*)carve((size_t)NN * HH * 4);
    ushort* hb   = (ushort*)carve((size_t)NN * HH * 2);
    // [po, ff1b, qb, kbf] are contiguous 16 MB -> aliased as lastE during setup
    float*  po   = (float*)carve((size_t)NN * HH * 4);
    ushort* ff1b = (ushort*)carve((size_t)NN * 4 * HH * 2);
    ushort* qb   = (ushort*)carve((size_t)NN * HH * 2);
    ushort* kbf  = (ushort*)carve((size_t)NN * HH * 2);
    ushort* vtb  = (ushort*)carve((size_t)NN * HH * 2);
    ushort* aob  = (ushort*)carve((size_t)NN * HH * 2);
    ushort* xb   = (ushort*)carve((size_t)NN * NF_ * 2);
    ushort* WnT  = (ushort*)carve((size_t)HH * NF_ * 2);
    ushort* WqkvT= (ushort*)carve((size_t)3 * HH * HH * 2);
    ushort* WoT  = (ushort*)carve((size_t)HH * HH * 2);
    ushort* W1T  = (ushort*)carve((size_t)4 * HH * HH * 2);
    ushort* W2T  = (ushort*)carve((size_t)4 * HH * HH * 2);
    float*  bqkv = (float*)carve((size_t)3 * HH * 4);
    float*  eb   = (float*)carve((size_t)EE * NHH * 4);
    float*  csr_b= (float*)carve((size_t)EE * NHH * 4);
    int* cnt     = (int*)carve((size_t)NN * 4);
    int* rowptr  = (int*)carve((size_t)(NN + 1) * 4);
    int* rowoff  = (int*)carve((size_t)NN * 4);
    int* csr_dst = (int*)carve((size_t)EE * 4);
    int* lastE = (int*)po;  // setup alias: po+ff1b+qb+kbf = 4+8+2+2 MB = 16 MB = NN*NN*4

    // ---- setup
    hipMemsetAsync(lastE, 0xFF, (size_t)NN * NN * 4, stream);   // -1
    hipMemsetAsync(cnt, 0, (size_t)NN * 4, stream);

    xcvt<<<(NN * NF_ + 255) / 256, 256, 0, stream>>>(x, xb, NN * NF_);
    wtrans<<<dim3(HH / 32, NF_ / 32), 256, 0, stream>>>(Wn, WnT, NF_, HH, 0);
    wtrans<<<dim3(HH / 32, HH / 32), 256, 0, stream>>>(Wq, WqkvT, HH, HH, 0);
    wtrans<<<dim3(HH / 32, HH / 32), 256, 0, stream>>>(Wk, WqkvT, HH, HH, 512);
    wtrans<<<dim3(HH / 32, HH / 32), 256, 0, stream>>>(Wv, WqkvT, HH, HH, 1024);
    wtrans<<<dim3(HH / 32, HH / 32), 256, 0, stream>>>(Wo, WoT, HH, HH, 0);
    wtrans<<<dim3(4 * HH / 32, HH / 32), 256, 0, stream>>>(W1, W1T, HH, 4 * HH, 0);
    wtrans<<<dim3(HH / 32, 4 * HH / 32), 256, 0, stream>>>(W2, W2T, 4 * HH, HH, 0);
    bconcat<<<6, 256, 0, stream>>>(bq, bk, bv, bqkv);

    ebias_kernel<<<EE / 256, 256, 0, stream>>>(ea, We, be, eb);
    amax_kernel<<<EE / 256, 256, 0, stream>>>(eidx, lastE);
    count_kernel<<<EE / 256, 256, 0, stream>>>(eidx, lastE, cnt);
    scan2048<<<1, 256, 0, stream>>>(cnt, rowptr, rowoff);
    fill_kernel<<<EE / 256, 256, 0, stream>>>(eidx, lastE, eb, rowoff, csr_dst, csr_b);

    // h = x @ Wn + bn  (f32 + bf16)
    gemm_mfma<64, 1, 0><<<dim3(HH / 64, NN / 128), 256, 0, stream>>>(
        xb, WnT, bn, h, hb, nullptr, nullptr, nullptr, NN, HH, NF_);

    // ---- transformer layers
    for (int d = 0; d < DEPTH; ++d) {
        gemm_mfma<128, 3, 0><<<dim3(3 * HH / 128, NN / 128), 256, 0, stream>>>(
            hb, WqkvT, bqkv, nullptr, nullptr, qb, kbf, vtb, NN, 3 * HH, HH);
        attn_mfma<<<dim3(NHH, NN / 32), 256, 0, stream>>>(qb, kbf, vtb, rowptr, csr_dst, csr_b, aob);
        gemm_mfma<64, 0, 0><<<dim3(HH / 64, NN / 128), 256, 0, stream>>>(
            aob, WoT, bo, po, nullptr, nullptr, nullptr, nullptr, NN, HH, HH);
        ln_kernel<1><<<NN / 4, 256, 0, stream>>>(h, po, g1, be1, h, hb);
        gemm_mfma<128, 2, 1><<<dim3(4 * HH / 128, NN / 128), 256, 0, stream>>>(
            hb, W1T, b1, nullptr, ff1b, nullptr, nullptr, nullptr, NN, 4 * HH, HH);
        gemm_mfma<64, 0, 0><<<dim3(HH / 64, NN / 128), 256, 0, stream>>>(
            ff1b, W2T, b2, po, nullptr, nullptr, nullptr, nullptr, NN, HH, 4 * HH);
        float* dst = (d == DEPTH - 1) ? out : h;
        ln_kernel<1><<<NN / 4, 256, 0, stream>>>(h, po, g2, be2, dst, hb);
    }
    (void)in_sizes; (void)n_in; (void)out_size; (void)ws_size;
}